// Round 16
// baseline (168.279 us; speedup 1.0000x reference)
//
#include <hip/hip_runtime.h>
#include <hip/hip_bf16.h>

constexpr int kB = 8, kN = 8192, kS = 2048;
constexpr int kD1 = 128, kD2 = 256, kCin = 384, kM0 = 256, kM1 = 128;
constexpr float kEps = 1e-5f;
constexpr int kReps = 64;   // stats-accumulator replicas (atomic decontention)

typedef float f32x4 __attribute__((ext_vector_type(4)));
typedef short bf16x8 __attribute__((ext_vector_type(8)));
typedef unsigned short u16x4 __attribute__((ext_vector_type(4)));

__device__ inline unsigned short f2bf(float f) {
    __hip_bfloat16 h = __float2bfloat16(f);
    return *reinterpret_cast<unsigned short*>(&h);
}
__device__ inline float bf2f(unsigned short u) {
    unsigned int v = (unsigned int)u << 16;
    return *reinterpret_cast<float*>(&v);
}
__device__ inline unsigned uminu(unsigned a, unsigned b) { return a < b ? a : b; }
__device__ inline unsigned med3u(unsigned a, unsigned b, unsigned c) {
    unsigned d;
    asm("v_med3_u32 %0, %1, %2, %3" : "=v"(d) : "v"(a), "v"(b), "v"(c));
    return d;
}
// sorted ascending top-4 insert: med3(x,k2,k3) == min(max(x,k2),k3)  -> 4 VALU
#define INS4(K0, K1, K2, K3, X) do { unsigned _x = (X);          \
    K3 = med3u(_x, K2, K3);                                      \
    K2 = med3u(_x, K1, K2);                                      \
    K1 = med3u(_x, K0, K1);                                      \
    K0 = uminu(_x, K0); } while (0)

// ---- prep: transposes + spk + stats zero + W f32->bf16, one dispatch ------
__global__ __launch_bounds__(256) void prep_kernel(
    const float* __restrict__ points2, float* __restrict__ p2t,
    const float* __restrict__ points1, unsigned short* __restrict__ xt,
    const float* __restrict__ xyz2, f32x4* __restrict__ spk,
    float* __restrict__ repl, float* __restrict__ smallstats,
    const float* __restrict__ w0, unsigned short* __restrict__ w0bf,
    const float* __restrict__ w1, unsigned short* __restrict__ w1bf)
{
    __shared__ float tl[64][69];
    const int bx = blockIdx.x;
    const int t = threadIdx.x;
    const int rlo = t >> 4, rhi = t & 15;
    if (bx < 1024) {
        const int b = bx >> 7, tile = bx & 127;
        const int s0 = (tile & 31) * 64, c0 = (tile >> 5) * 64;
#pragma unroll
        for (int r = 0; r < 4; ++r) {
            const int cl = rlo + r * 16;
            f32x4 v = *(const f32x4*)(points2 + ((size_t)(b * kD2 + c0 + cl)) * kS + s0 + rhi * 4);
#pragma unroll
            for (int j = 0; j < 4; ++j) tl[cl][rhi * 4 + j] = v[j];
        }
        __syncthreads();
#pragma unroll
        for (int r = 0; r < 4; ++r) {
            const int sl = rlo + r * 16;
            f32x4 v;
#pragma unroll
            for (int j = 0; j < 4; ++j) v[j] = tl[rhi * 4 + j][sl];
            *(f32x4*)(p2t + ((size_t)(b * kS + s0 + sl)) * kD2 + c0 + rhi * 4) = v;
        }
    } else if (bx < 3072) {
        const int idx = bx - 1024;
        const int b = idx >> 8, tile = idx & 255;
        const int n0 = (tile & 127) * 64, c0 = (tile >> 7) * 64;
#pragma unroll
        for (int r = 0; r < 4; ++r) {
            const int cl = rlo + r * 16;
            f32x4 v = *(const f32x4*)(points1 + ((size_t)(b * kD1 + c0 + cl)) * kN + n0 + rhi * 4);
#pragma unroll
            for (int j = 0; j < 4; ++j) tl[cl][rhi * 4 + j] = v[j];
        }
        __syncthreads();
#pragma unroll
        for (int r = 0; r < 4; ++r) {
            const int nl = rlo + r * 16;
            u16x4 u;
#pragma unroll
            for (int j = 0; j < 4; ++j) u[j] = f2bf(tl[rhi * 4 + j][nl]);
            *(u16x4*)(xt + ((size_t)(b * kN + n0 + nl)) * kCin + 256 + c0 + rhi * 4) = u;
        }
    } else if (bx < 3080) {
        const int b = bx - 3072;
        const float* x2 = xyz2 + b * 3 * kS;
        for (int s = t; s < kS; s += 256) {
            float sx = x2[s], sy = x2[kS + s], sz = x2[2 * kS + s];
            f32x4 q = {sx, sy, sz, fmaf(sx, sx, fmaf(sy, sy, sz * sz))};
            spk[b * kS + s] = q;
        }
        // zero this block's slice of the replicated stats (49152 floats total)
        for (int i = b * 6144 + t; i < (b + 1) * 6144; i += 256) repl[i] = 0.f;
        if (b == 0) for (int i = t; i < 772; i += 256) smallstats[i] = 0.f;
    } else if (bx < 3096) {
        const int base = (bx - 3080) * 256 + t;           // 4096 threads
        for (int c = base; c < kM0 * kCin / 4; c += 4096) {
            f32x4 v = *(const f32x4*)(w0 + (size_t)c * 4);
            u16x4 u = {f2bf(v[0]), f2bf(v[1]), f2bf(v[2]), f2bf(v[3])};
            *(u16x4*)(w0bf + (size_t)c * 4) = u;
        }
    } else {
        const int base = (bx - 3096) * 256 + t;           // 2048 threads
        for (int c = base; c < kM1 * kM0 / 4; c += 2048) {
            f32x4 v = *(const f32x4*)(w1 + (size_t)c * 4);
            u16x4 u = {f2bf(v[0]), f2bf(v[1]), f2bf(v[2]), f2bf(v[3])};
            *(u16x4*)(w1bf + (size_t)c * 4) = u;
        }
    }
}

// ------- 3-NN + interp: TWO-PASS (min-chain bound -> rare insert) ----------
// r14 layout (validated): 16 threads/query-group, 4 queries/thread, sources
// s = l16 + 16i. r14 measured 23 VALU ops/pair -- the always-taken INS4.
// pass1: 2 clamped min-chains/query/lane (1 fmin/pair). The 32 chain minima
//        per query are 32 DISTINCT elements -> 3rd-smallest chain-min >=
//        true e(3) (usually ==, collision prob ~9%). Sorted-triple butterfly
//        merge (r3-validated network) -> cutoff = bound + 1e-3.
// pass2: recompute e; only candidates e<=cutoff (expected ~4-5/query) enter
//        the key INS4, behind a wave-uniform __any skip (~85% steps skipped).
//        Keys identical to r14; excluded elements provably can't displace
//        top-3 keys (gap > 1e-3 >> fp32 err + 2^-12 quant). If <4 candidates
//        pass, k3 stays INF -> v3t = NaN -> flag=false (correct: certified).
// Then fp64 rescore + gap-certify + ballot compaction (r14 verbatim);
// flagged queries redone by the SEPARATE fallback kernel (r15's in-block
// fallback serialized blocks: 52.7 -> 69.4us; reverted).
__global__ __launch_bounds__(256) void knn_interp_kernel(
    const float* __restrict__ xyz1, const f32x4* __restrict__ spk,
    const float* __restrict__ p2t, unsigned short* __restrict__ xt,
    int* __restrict__ flaglist, int* __restrict__ flagcount)
{
    __shared__ f32x4 sp[kS];                 // 32 KB
    __shared__ float gw[64][3];
    __shared__ int   gi[64][3];
    const int bb = blockIdx.x >> 7;          // 128 blocks per batch
    const int nblk = (blockIdx.x & 127) << 6;
    const int t = threadIdx.x;
    for (int s = t; s < kS; s += 256) sp[s] = spk[bb * kS + s];
    __syncthreads();
    const int grp = t >> 4, l16 = t & 15;    // 16 groups x 16 lanes
    const int q0 = nblk + grp * 4;           // this group's 4 queries
    const float* x1 = xyz1 + bb * 3 * kN;
    float ax[4], ay[4], az[4], ppv[4];
#pragma unroll
    for (int j = 0; j < 4; ++j) {
        const float px = x1[q0 + j], py = x1[kN + q0 + j], pz = x1[2 * kN + q0 + j];
        ax[j] = -2.f * px; ay[j] = -2.f * py; az[j] = -2.f * pz;
        ppv[j] = fmaf(px, px, fmaf(py, py, pz * pz));
    }

    // ---- pass 1: two clamped min-chains per query (even/odd i)
    float cA[4], cB[4];
#pragma unroll
    for (int j = 0; j < 4; ++j) { cA[j] = 1e30f; cB[j] = 1e30f; }
#pragma unroll 2
    for (int i = 0; i < 128; i += 2) {
        const f32x4 qv0 = sp[l16 + 16 * i];
        const f32x4 qv1 = sp[l16 + 16 * (i + 1)];
#pragma unroll
        for (int j = 0; j < 4; ++j) {
            const float e0 = fmaxf(fmaf(ax[j], qv0[0], fmaf(ay[j], qv0[1],
                                 fmaf(az[j], qv0[2], qv0[3] + ppv[j]))), 0.f);
            const float e1 = fmaxf(fmaf(ax[j], qv1[0], fmaf(ay[j], qv1[1],
                                 fmaf(az[j], qv1[2], qv1[3] + ppv[j]))), 0.f);
            cA[j] = fminf(cA[j], e0);
            cB[j] = fminf(cB[j], e1);
        }
    }
    // per-lane sorted triple, then butterfly-merge across the 16-lane group
    float b0[4], b1[4], b2[4];
#pragma unroll
    for (int j = 0; j < 4; ++j) {
        b0[j] = fminf(cA[j], cB[j]); b1[j] = fmaxf(cA[j], cB[j]); b2[j] = 1e30f;
    }
#pragma unroll
    for (int off = 1; off <= 8; off <<= 1) {
#pragma unroll
        for (int j = 0; j < 4; ++j) {
            const float y0 = __shfl_xor(b0[j], off), y1 = __shfl_xor(b1[j], off), y2 = __shfl_xor(b2[j], off);
            const float z0 = fminf(b0[j], y0);
            const float z1 = fminf(fmaxf(b0[j], y0), fminf(b1[j], y1));
            const float z2 = fminf(fminf(fmaxf(b1[j], y0), fmaxf(b0[j], y1)), fminf(b2[j], y2));
            b0[j] = z0; b1[j] = z1; b2[j] = z2;
        }
    }
    float cut[4];
#pragma unroll
    for (int j = 0; j < 4; ++j) cut[j] = b2[j] + 1e-3f;

    // ---- pass 2: filtered key top-4 (insert only for candidates)
    unsigned ka[4], kb[4], kc[4], kd[4];
#pragma unroll
    for (int j = 0; j < 4; ++j) { ka[j] = kb[j] = kc[j] = kd[j] = 0xFFFFFFFFu; }
#pragma unroll 2
    for (int i = 0; i < 128; ++i) {
        const int s = l16 + 16 * i;
        const f32x4 qv = sp[s];
        float e[4]; int cnd[4];
#pragma unroll
        for (int j = 0; j < 4; ++j) {
            e[j] = fmaxf(fmaf(ax[j], qv[0], fmaf(ay[j], qv[1],
                        fmaf(az[j], qv[2], qv[3] + ppv[j]))), 0.f);
            cnd[j] = e[j] <= cut[j];
        }
        if (__any(cnd[0] | cnd[1] | cnd[2] | cnd[3])) {
#pragma unroll
            for (int j = 0; j < 4; ++j) {
                const unsigned x = cnd[j]
                    ? ((__float_as_uint(e[j]) & 0xFFFFF800u) | (unsigned)s)
                    : 0xFFFFFFFFu;
                INS4(ka[j], kb[j], kc[j], kd[j], x);
            }
        }
    }
    // butterfly merge keys across the 16-lane group
#pragma unroll
    for (int off = 1; off <= 8; off <<= 1) {
#pragma unroll
        for (int j = 0; j < 4; ++j) {
            const unsigned m0 = __shfl_xor(ka[j], off), m1 = __shfl_xor(kb[j], off);
            const unsigned m2 = __shfl_xor(kc[j], off), m3 = __shfl_xor(kd[j], off);
            INS4(ka[j], kb[j], kc[j], kd[j], m0); INS4(ka[j], kb[j], kc[j], kd[j], m1);
            INS4(ka[j], kb[j], kc[j], kd[j], m2); INS4(ka[j], kb[j], kc[j], kd[j], m3);
        }
    }

    // lanes l16<4 finalize query (grp*4 + l16); chains identical on all 16
    // lanes, so select chain l16 via compile-time ternaries (no scratch).
    bool flag = false;
    if (l16 < 4) {
        const unsigned c0 = l16 == 0 ? ka[0] : l16 == 1 ? ka[1] : l16 == 2 ? ka[2] : ka[3];
        const unsigned c1 = l16 == 0 ? kb[0] : l16 == 1 ? kb[1] : l16 == 2 ? kb[2] : kb[3];
        const unsigned c2 = l16 == 0 ? kc[0] : l16 == 1 ? kc[1] : l16 == 2 ? kc[2] : kc[3];
        const unsigned c3 = l16 == 0 ? kd[0] : l16 == 1 ? kd[1] : l16 == 2 ? kd[2] : kd[3];
        const float axx = l16 == 0 ? ax[0] : l16 == 1 ? ax[1] : l16 == 2 ? ax[2] : ax[3];
        const float ayy = l16 == 0 ? ay[0] : l16 == 1 ? ay[1] : l16 == 2 ? ay[2] : ay[3];
        const float azz = l16 == 0 ? az[0] : l16 == 1 ? az[1] : l16 == 2 ? az[2] : az[3];
        int i0 = (int)(c0 & 2047u), i1 = (int)(c1 & 2047u), i2 = (int)(c2 & 2047u);
        const float v2t = __uint_as_float(c2 & 0xFFFFF800u);
        const float v3t = __uint_as_float(c3 & 0xFFFFF800u);   // NaN if k3==INF -> flag false (certified)
        flag = (v3t - v2t) <= fmaf(v3t, 1e-3f, 2.5e-4f);
        // fp64 rescore of the 3 chosen: exact order + exact weights
        const double dpx = -0.5 * (double)axx, dpy = -0.5 * (double)ayy, dpz = -0.5 * (double)azz;
        const f32x4 s0 = sp[i0], s1 = sp[i1], s2 = sp[i2];
        double d0 = (dpx - s0[0]) * (dpx - s0[0]) + (dpy - s0[1]) * (dpy - s0[1]) + (dpz - s0[2]) * (dpz - s0[2]);
        double d1 = (dpx - s1[0]) * (dpx - s1[0]) + (dpy - s1[1]) * (dpy - s1[1]) + (dpz - s1[2]) * (dpz - s1[2]);
        double d2 = (dpx - s2[0]) * (dpx - s2[0]) + (dpy - s2[1]) * (dpy - s2[1]) + (dpz - s2[2]) * (dpz - s2[2]);
        if (d1 < d0 || (d1 == d0 && i1 < i0)) { double td = d0; d0 = d1; d1 = td; int ti = i0; i0 = i1; i1 = ti; }
        if (d2 < d1 || (d2 == d1 && i2 < i1)) { double td = d1; d1 = d2; d2 = td; int ti = i1; i1 = i2; i2 = ti; }
        if (d1 < d0 || (d1 == d0 && i1 < i0)) { double td = d0; d0 = d1; d1 = td; int ti = i0; i0 = i1; i1 = ti; }
        const double r0 = 1.0 / (d0 + 1e-8), r1 = 1.0 / (d1 + 1e-8), r2 = 1.0 / (d2 + 1e-8);
        const double rs = 1.0 / (r0 + r1 + r2);
        const int gq = grp * 4 + l16;
        gw[gq][0] = (float)(r0 * rs); gw[gq][1] = (float)(r1 * rs); gw[gq][2] = (float)(r2 * rs);
        gi[gq][0] = i0; gi[gq][1] = i1; gi[gq][2] = i2;
    }
    // compact flagged queries: ballot + one atomic per wave
    {
        const unsigned long long bal = __ballot(flag);
        if (bal) {
            const int l = t & 63;
            int base = 0;
            if (l == 0) base = atomicAdd(flagcount, __popcll(bal));
            base = __shfl(base, 0);
            if (flag) {
                const int pre = __popcll(bal & ((1ull << l) - 1ull));
                flaglist[base + pre] = (bb << 13) | (nblk + grp * 4 + l16);
            }
        }
    }
    __syncthreads();

    // gather: 3 contiguous 1 KB p2t rows per query, 4 threads per query
    const int q = t >> 2, c4 = t & 3;
    const int nq = nblk + q;
    const float w0f = gw[q][0], w1f = gw[q][1], w2f = gw[q][2];
    const f32x4* row0 = (const f32x4*)(p2t + ((size_t)(bb * kS) + gi[q][0]) * kD2);
    const f32x4* row1 = (const f32x4*)(p2t + ((size_t)(bb * kS) + gi[q][1]) * kD2);
    const f32x4* row2 = (const f32x4*)(p2t + ((size_t)(bb * kS) + gi[q][2]) * kD2);
    unsigned short* dst = xt + ((size_t)(bb * kN) + nq) * kCin;
#pragma unroll 4
    for (int j = 0; j < 16; ++j) {
        const int ch = c4 + 4 * j;
        f32x4 v = w0f * row0[ch] + w1f * row1[ch] + w2f * row2[ch];
        u16x4 u = {f2bf(v[0]), f2bf(v[1]), f2bf(v[2]), f2bf(v[3])};
        *(u16x4*)(dst + ch * 4) = u;
    }
}
#undef INS4

// ---- Exact fp64 redo for uncertified queries (one wave per query) ---------
__global__ __launch_bounds__(256) void knn_fallback_kernel(
    const float* __restrict__ xyz1, const f32x4* __restrict__ spk,
    const float* __restrict__ p2t, unsigned short* __restrict__ xt,
    const int* __restrict__ flaglist, const int* __restrict__ flagcount)
{
    const int cnt = *flagcount;
    const int t = threadIdx.x;
    const int w = t >> 6, l = t & 63;
    for (int idx = blockIdx.x * 4 + w; idx < cnt; idx += gridDim.x * 4) {
        const int code = flaglist[idx];
        const int b = code >> 13, n = code & 8191;
        const float* x1 = xyz1 + b * 3 * kN;
        const double px = (double)x1[n], py = (double)x1[kN + n], pz = (double)x1[2 * kN + n];
        double d0 = 1e300, d1 = 1e300, d2 = 1e300;
        int i0 = 0, i1 = 0, i2 = 0;
        for (int s = l; s < kS; s += 64) {
            const f32x4 q = spk[b * kS + s];
            const double ex = px - (double)q[0], ey = py - (double)q[1], ez = pz - (double)q[2];
            const double d = ex * ex + ey * ey + ez * ez;
            if (d < d2) {
                if (d < d1) {
                    if (d < d0) { d2 = d1; i2 = i1; d1 = d0; i1 = i0; d0 = d; i0 = s; }
                    else        { d2 = d1; i2 = i1; d1 = d;  i1 = s; }
                } else          { d2 = d;  i2 = s; }
            }
        }
#pragma unroll
        for (int off = 1; off < 64; off <<= 1) {
            double pd0 = __shfl_xor(d0, off), pd1 = __shfl_xor(d1, off), pd2 = __shfl_xor(d2, off);
            int pi0 = __shfl_xor(i0, off), pi1 = __shfl_xor(i1, off), pi2 = __shfl_xor(i2, off);
#pragma unroll
            for (int m = 0; m < 3; ++m) {
                const double pd = (m == 0) ? pd0 : (m == 1) ? pd1 : pd2;
                const int pi = (m == 0) ? pi0 : (m == 1) ? pi1 : pi2;
                if (pd < d2 || (pd == d2 && pi < i2)) {
                    if (pd < d1 || (pd == d1 && pi < i1)) {
                        if (pd < d0 || (pd == d0 && pi < i0)) {
                            d2 = d1; i2 = i1; d1 = d0; i1 = i0; d0 = pd; i0 = pi;
                        } else { d2 = d1; i2 = i1; d1 = pd; i1 = pi; }
                    } else { d2 = pd; i2 = pi; }
                }
            }
        }
        const double r0 = 1.0 / (d0 + 1e-8), r1 = 1.0 / (d1 + 1e-8), r2 = 1.0 / (d2 + 1e-8);
        const double rs = 1.0 / (r0 + r1 + r2);
        const float w0f = (float)(r0 * rs), w1f = (float)(r1 * rs), w2f = (float)(r2 * rs);
        const f32x4* row0 = (const f32x4*)(p2t + ((size_t)(b * kS) + i0) * kD2);
        const f32x4* row1 = (const f32x4*)(p2t + ((size_t)(b * kS) + i1) * kD2);
        const f32x4* row2 = (const f32x4*)(p2t + ((size_t)(b * kS) + i2) * kD2);
        const f32x4 v = w0f * row0[l] + w1f * row1[l] + w2f * row2[l];
        u16x4 u = {f2bf(v[0]), f2bf(v[1]), f2bf(v[2]), f2bf(v[3])};
        *(u16x4*)(xt + ((size_t)(b * kN) + n) * kCin + l * 4) = u;
    }
}

// ---------------- bf16 MFMA GEMM + BN-stats, double-buffered ---------------
// Stats to 64 replicated accumulators (repl[rep][2*MTOT]) -> <=16 atomic
// colliders/address (r13 fix for the 53us flat atomic-serialization cost).
__device__ inline int swz(int row, int ks) {   // ushort index of a 16B slot
    return row * 32 + ((ks ^ ((row >> 1) & 3)) << 3);
}

template <int K, int MTOT, bool BNRELU, int OUTMODE, bool STATS>
__global__ __launch_bounds__(256) void gemm_bn_kernel(
    const unsigned short* __restrict__ Wbf, const unsigned short* __restrict__ X,
    const float* __restrict__ scale, const float* __restrict__ shift,
    unsigned short* __restrict__ Yb, float* __restrict__ Yf,
    float* __restrict__ repl)
{
    constexpr int BM = 128, BN = 64;
    __shared__ unsigned short Al[2][BM * 32], Bl[2][BN * 32];   // 16+8 KB
    __shared__ float ssum[BM], ssq[BM];
    __shared__ float s_sc[K], s_sh[K];
    const int t = threadIdx.x;
    const int bn = blockIdx.x * BN, bo = blockIdx.y * BM, b = blockIdx.z;
    const int l = t & 63, w = t >> 6;
    const int wm = (w >> 1) * 64, wn = (w & 1) * 32;
    const int lrow = l & 15, lks = l >> 4;

    if constexpr (BNRELU) {
        if (t < K) { s_sc[t] = scale[t]; s_sh[t] = shift[t]; }
    }
    if constexpr (STATS) {
        if (t < BM) { ssum[t] = 0.f; ssq[t] = 0.f; }
    }
    __syncthreads();

    const int mA0 = t >> 2, ksA = t & 3;
    const int mA1 = mA0 + 64;
    const int nB = t >> 2, ksB = t & 3;
    bf16x8 rA0, rA1, rB;

    auto load_tile = [&](int k0) {
        rA0 = *(const bf16x8*)(Wbf + (size_t)(bo + mA0) * K + k0 + ksA * 8);
        rA1 = *(const bf16x8*)(Wbf + (size_t)(bo + mA1) * K + k0 + ksA * 8);
        rB  = *(const bf16x8*)(X + ((size_t)(b * kN) + bn + nB) * K + k0 + ksB * 8);
    };
    auto write_tile = [&](int buf, int k0) {
        *(bf16x8*)(&Al[buf][0] + swz(mA0, ksA)) = rA0;
        *(bf16x8*)(&Al[buf][0] + swz(mA1, ksA)) = rA1;
        bf16x8 v = rB;
        if constexpr (BNRELU) {
#pragma unroll
            for (int j = 0; j < 8; ++j) {
                const int ch = k0 + ksB * 8 + j;
                float f = fmaxf(fmaf(bf2f((unsigned short)v[j]), s_sc[ch], s_sh[ch]), 0.f);
                v[j] = (short)f2bf(f);
            }
        }
        *(bf16x8*)(&Bl[buf][0] + swz(nB, ksB)) = v;
    };

    f32x4 acc[4][2] = {};
    load_tile(0);
    write_tile(0, 0);
    __syncthreads();
    int cur = 0;
    for (int k0 = 32; k0 <= K; k0 += 32) {
        if (k0 < K) load_tile(k0);             // prefetch next tile to regs
        bf16x8 af[4], bfr[2];
#pragma unroll
        for (int f = 0; f < 4; ++f) af[f]  = *(const bf16x8*)(&Al[cur][0] + swz(wm + f * 16 + lrow, lks));
#pragma unroll
        for (int f = 0; f < 2; ++f) bfr[f] = *(const bf16x8*)(&Bl[cur][0] + swz(wn + f * 16 + lrow, lks));
#pragma unroll
        for (int mi = 0; mi < 4; ++mi)
#pragma unroll
            for (int ni = 0; ni < 2; ++ni)
                acc[mi][ni] = __builtin_amdgcn_mfma_f32_16x16x32_bf16(af[mi], bfr[ni], acc[mi][ni], 0, 0, 0);
        if (k0 < K) { write_tile(cur ^ 1, k0); cur ^= 1; }
        __syncthreads();
    }

    if constexpr (STATS) {
#pragma unroll
        for (int mi = 0; mi < 4; ++mi) {
#pragma unroll
            for (int r = 0; r < 4; ++r) {
                float ps = 0.f, pq = 0.f;
#pragma unroll
                for (int ni = 0; ni < 2; ++ni) { float v = acc[mi][ni][r]; ps += v; pq += v * v; }
#pragma unroll
                for (int off = 1; off < 16; off <<= 1) { ps += __shfl_xor(ps, off); pq += __shfl_xor(pq, off); }
                if (lrow == 0) {
                    const int m = wm + mi * 16 + lks * 4 + r;
                    atomicAdd(&ssum[m], ps); atomicAdd(&ssq[m], pq);
                }
            }
        }
    }

    if constexpr (OUTMODE == 0) {
#pragma unroll
        for (int mi = 0; mi < 4; ++mi)
#pragma unroll
            for (int ni = 0; ni < 2; ++ni) {
                const int m = bo + wm + mi * 16 + lks * 4;
                const int n = bn + wn + ni * 16 + lrow;
                u16x4 u = {f2bf(acc[mi][ni][0]), f2bf(acc[mi][ni][1]),
                           f2bf(acc[mi][ni][2]), f2bf(acc[mi][ni][3])};
                *(u16x4*)(Yb + ((size_t)(b * kN) + n) * MTOT + m) = u;
            }
    } else {
#pragma unroll
        for (int mi = 0; mi < 4; ++mi)
#pragma unroll
            for (int ni = 0; ni < 2; ++ni) {
                const int n = bn + wn + ni * 16 + lrow;
#pragma unroll
                for (int r = 0; r < 4; ++r) {
                    const int m = bo + wm + mi * 16 + lks * 4 + r;
                    Yf[((size_t)(b * MTOT) + m) * kN + n] = acc[mi][ni][r];
                }
            }
    }
    if constexpr (STATS) {
        __syncthreads();
        if (t < BM) {
            const int rep = (blockIdx.x + blockIdx.z * 8) & (kReps - 1);
            float* rp = repl + (size_t)rep * (2 * MTOT);
            atomicAdd(&rp[bo + t], ssum[t]);
            atomicAdd(&rp[MTOT + bo + t], ssq[t]);
        }
    }
}

// ---- BN finalize: sum 64 replicas -> scale/shift (tiny, 1 block) ----------
__global__ void bn_finalize_kernel(const float* __restrict__ repl,
                                   const float* __restrict__ g, const float* __restrict__ be,
                                   float* __restrict__ scale, float* __restrict__ shift, int M)
{
    const int t = threadIdx.x;
    if (t < M) {
        float s = 0.f, q = 0.f;
#pragma unroll 8
        for (int r = 0; r < kReps; ++r) {
            s += repl[(size_t)r * 2 * M + t];
            q += repl[(size_t)r * 2 * M + M + t];
        }
        const float invn = 1.0f / 65536.0f;
        const float mean = s * invn;
        const float var = q * invn - mean * mean;   // biased var
        const float sc = g[t] * rsqrtf(var + kEps);
        scale[t] = sc;
        shift[t] = fmaf(-mean, sc, be[t]);
    }
}

// -------- Final in-place BN+ReLU on d_out ----------------------------------
__global__ __launch_bounds__(256) void bn_relu_out_kernel(
    float* __restrict__ out, const float* __restrict__ scale, const float* __restrict__ shift)
{
    const int total = kB * kM1 * kN / 4;
    for (int idx = blockIdx.x * blockDim.x + threadIdx.x; idx < total;
         idx += gridDim.x * blockDim.x) {
        const int p = (idx >> 11) & 127;
        const float sc = scale[p], sh = shift[p];
        f32x4 v = ((f32x4*)out)[idx];
#pragma unroll
        for (int j = 0; j < 4; ++j) v[j] = fmaxf(fmaf(v[j], sc, sh), 0.f);
        ((f32x4*)out)[idx] = v;
    }
}

extern "C" void kernel_launch(void* const* d_in, const int* in_sizes, int n_in,
                              void* d_out, int out_size, void* d_ws, size_t ws_size,
                              hipStream_t stream)
{
    const float* xyz1    = (const float*)d_in[0];
    const float* xyz2    = (const float*)d_in[1];
    const float* points1 = (const float*)d_in[2];
    const float* points2 = (const float*)d_in[3];
    const float* w0      = (const float*)d_in[4];
    // d_in[5] = b0, d_in[9] = b1: conv biases cancel in BatchNorm -> unused
    const float* g0      = (const float*)d_in[6];
    const float* be0     = (const float*)d_in[7];
    const float* w1      = (const float*)d_in[8];
    const float* g1      = (const float*)d_in[10];
    const float* be1     = (const float*)d_in[11];
    float* out = (float*)d_out;

    char* ws = (char*)d_ws;
    unsigned short* xt  = (unsigned short*)ws;                           // 48 MiB  [B][N][384] bf16
    float* p2t          = (float*)(ws + (size_t)50331648);               // 16 MiB  [B][S][256] f32
    unsigned short* y0t = (unsigned short*)(ws + (size_t)67108864);      // 32 MiB  [B][N][256] bf16
    float* repl0        = (float*)(ws + (size_t)100663296);              // 128 KiB [64][512]
    float* repl1        = (float*)(ws + (size_t)100794368);              // 64 KiB  [64][256]
    float* smallstats   = (float*)(ws + (size_t)100859904);              // 772 floats
    f32x4* spk          = (f32x4*)(ws + (size_t)104857600);              // 256 KiB [B][S] packed
    int*  flaglist      = (int*)(ws + (size_t)105906176);                // 256 KiB worst-case
    unsigned short* w0bf = (unsigned short*)(ws + (size_t)106954752);    // 192 KiB [256][384] bf16
    unsigned short* w1bf = (unsigned short*)(ws + (size_t)107151360);    // 64 KiB  [128][256] bf16
    float* scale0 = smallstats,       *shift0 = smallstats + 256;
    float* scale1 = smallstats + 512, *shift1 = smallstats + 640;
    int*  flagcount = (int*)(smallstats + 768);

    prep_kernel<<<3104, 256, 0, stream>>>(points2, p2t, points1, xt, xyz2, spk,
                                          repl0, smallstats, w0, w0bf, w1, w1bf);
    knn_interp_kernel<<<1024, 256, 0, stream>>>(xyz1, spk, p2t, xt, flaglist, flagcount);
    knn_fallback_kernel<<<1024, 256, 0, stream>>>(xyz1, spk, p2t, xt, flaglist, flagcount);
    gemm_bn_kernel<kCin, kM0, false, 0, true><<<dim3(128, 2, 8), 256, 0, stream>>>(
        w0bf, xt, nullptr, nullptr, y0t, nullptr, repl0);
    bn_finalize_kernel<<<1, 256, 0, stream>>>(repl0, g0, be0, scale0, shift0, 256);
    gemm_bn_kernel<kM0, kM1, true, 1, true><<<dim3(128, 1, 8), 256, 0, stream>>>(
        w1bf, y0t, scale0, shift0, nullptr, out, repl1);
    bn_finalize_kernel<<<1, 128, 0, stream>>>(repl1, g1, be1, scale1, shift1, 128);
    bn_relu_out_kernel<<<2048, 256, 0, stream>>>(out, scale1, shift1);
}

// Round 17
// 157.576 us; speedup vs baseline: 1.0679x; 1.0679x over previous
//
#include <hip/hip_runtime.h>
#include <hip/hip_bf16.h>

constexpr int kB = 8, kN = 8192, kS = 2048;
constexpr int kD1 = 128, kD2 = 256, kCin = 384, kM0 = 256, kM1 = 128;
constexpr float kEps = 1e-5f;
constexpr int kReps = 64;   // stats-accumulator replicas (atomic decontention)

typedef float f32x4 __attribute__((ext_vector_type(4)));
typedef short bf16x8 __attribute__((ext_vector_type(8)));
typedef unsigned short u16x4 __attribute__((ext_vector_type(4)));

__device__ inline unsigned short f2bf(float f) {
    __hip_bfloat16 h = __float2bfloat16(f);
    return *reinterpret_cast<unsigned short*>(&h);
}
__device__ inline float bf2f(unsigned short u) {
    unsigned int v = (unsigned int)u << 16;
    return *reinterpret_cast<float*>(&v);
}
__device__ inline unsigned uminu(unsigned a, unsigned b) { return a < b ? a : b; }
__device__ inline unsigned med3u(unsigned a, unsigned b, unsigned c) {
    unsigned d;
    asm("v_med3_u32 %0, %1, %2, %3" : "=v"(d) : "v"(a), "v"(b), "v"(c));
    return d;
}
// sorted ascending top-4 insert: med3(x,k2,k3) == min(max(x,k2),k3)  -> 4 VALU
#define INS4(K0, K1, K2, K3, X) do { unsigned _x = (X);          \
    K3 = med3u(_x, K2, K3);                                      \
    K2 = med3u(_x, K1, K2);                                      \
    K1 = med3u(_x, K0, K1);                                      \
    K0 = uminu(_x, K0); } while (0)

// ---- prep: transposes + spk + stats zero + W f32->bf16, one dispatch ------
__global__ __launch_bounds__(256) void prep_kernel(
    const float* __restrict__ points2, float* __restrict__ p2t,
    const float* __restrict__ points1, unsigned short* __restrict__ xt,
    const float* __restrict__ xyz2, f32x4* __restrict__ spk,
    float* __restrict__ repl, float* __restrict__ smallstats,
    const float* __restrict__ w0, unsigned short* __restrict__ w0bf,
    const float* __restrict__ w1, unsigned short* __restrict__ w1bf)
{
    __shared__ float tl[64][69];
    const int bx = blockIdx.x;
    const int t = threadIdx.x;
    const int rlo = t >> 4, rhi = t & 15;
    if (bx < 1024) {
        const int b = bx >> 7, tile = bx & 127;
        const int s0 = (tile & 31) * 64, c0 = (tile >> 5) * 64;
#pragma unroll
        for (int r = 0; r < 4; ++r) {
            const int cl = rlo + r * 16;
            f32x4 v = *(const f32x4*)(points2 + ((size_t)(b * kD2 + c0 + cl)) * kS + s0 + rhi * 4);
#pragma unroll
            for (int j = 0; j < 4; ++j) tl[cl][rhi * 4 + j] = v[j];
        }
        __syncthreads();
#pragma unroll
        for (int r = 0; r < 4; ++r) {
            const int sl = rlo + r * 16;
            f32x4 v;
#pragma unroll
            for (int j = 0; j < 4; ++j) v[j] = tl[rhi * 4 + j][sl];
            *(f32x4*)(p2t + ((size_t)(b * kS + s0 + sl)) * kD2 + c0 + rhi * 4) = v;
        }
    } else if (bx < 3072) {
        const int idx = bx - 1024;
        const int b = idx >> 8, tile = idx & 255;
        const int n0 = (tile & 127) * 64, c0 = (tile >> 7) * 64;
#pragma unroll
        for (int r = 0; r < 4; ++r) {
            const int cl = rlo + r * 16;
            f32x4 v = *(const f32x4*)(points1 + ((size_t)(b * kD1 + c0 + cl)) * kN + n0 + rhi * 4);
#pragma unroll
            for (int j = 0; j < 4; ++j) tl[cl][rhi * 4 + j] = v[j];
        }
        __syncthreads();
#pragma unroll
        for (int r = 0; r < 4; ++r) {
            const int nl = rlo + r * 16;
            u16x4 u;
#pragma unroll
            for (int j = 0; j < 4; ++j) u[j] = f2bf(tl[rhi * 4 + j][nl]);
            *(u16x4*)(xt + ((size_t)(b * kN + n0 + nl)) * kCin + 256 + c0 + rhi * 4) = u;
        }
    } else if (bx < 3080) {
        const int b = bx - 3072;
        const float* x2 = xyz2 + b * 3 * kS;
        for (int s = t; s < kS; s += 256) {
            float sx = x2[s], sy = x2[kS + s], sz = x2[2 * kS + s];
            f32x4 q = {sx, sy, sz, fmaf(sx, sx, fmaf(sy, sy, sz * sz))};
            spk[b * kS + s] = q;
        }
        // zero this block's slice of the replicated stats (49152 floats total)
        for (int i = b * 6144 + t; i < (b + 1) * 6144; i += 256) repl[i] = 0.f;
        if (b == 0) for (int i = t; i < 772; i += 256) smallstats[i] = 0.f;
    } else if (bx < 3096) {
        const int base = (bx - 3080) * 256 + t;           // 4096 threads
        for (int c = base; c < kM0 * kCin / 4; c += 4096) {
            f32x4 v = *(const f32x4*)(w0 + (size_t)c * 4);
            u16x4 u = {f2bf(v[0]), f2bf(v[1]), f2bf(v[2]), f2bf(v[3])};
            *(u16x4*)(w0bf + (size_t)c * 4) = u;
        }
    } else {
        const int base = (bx - 3096) * 256 + t;           // 2048 threads
        for (int c = base; c < kM1 * kM0 / 4; c += 2048) {
            f32x4 v = *(const f32x4*)(w1 + (size_t)c * 4);
            u16x4 u = {f2bf(v[0]), f2bf(v[1]), f2bf(v[2]), f2bf(v[3])};
            *(u16x4*)(w1bf + (size_t)c * 4) = u;
        }
    }
}

// ------- 3-NN + interp: 1-pass LDS scan + u32-key top-4 (r13, BEST) --------
// 4 threads/query; per pair: 1 ds_read_b128 (amortized over quad) + fma
// chain + key pack + med3 INS4. r13 measured 52.1-52.4us, VALU-bound 77%.
// r14 (amortized reads), r15 (in-block fallback), r16 (two-pass filter) all
// regressed or null -> this is the empirical VALU floor for 134M pairs.
__global__ __launch_bounds__(256) void knn_interp_kernel(
    const float* __restrict__ xyz1, const f32x4* __restrict__ spk,
    const float* __restrict__ p2t, unsigned short* __restrict__ xt,
    int* __restrict__ flaglist, int* __restrict__ flagcount)
{
    __shared__ f32x4 sp[kS];                 // 32 KB
    const int bb = blockIdx.x >> 7;          // 128 blocks per batch
    const int nblk = (blockIdx.x & 127) << 6;
    const int t = threadIdx.x;
    for (int s = t; s < kS; s += 256) sp[s] = spk[bb * kS + s];
    __syncthreads();
    const int q = t >> 2, c = t & 3;
    const int nq = nblk + q;
    const float* x1 = xyz1 + bb * 3 * kN;
    const float px = x1[nq], py = x1[kN + nq], pz = x1[2 * kN + nq];
    const float ax = -2.f * px, ay = -2.f * py, az = -2.f * pz;
    const float pp = fmaf(px, px, fmaf(py, py, pz * pz));

    unsigned k0 = 0xFFFFFFFFu, k1 = 0xFFFFFFFFu, k2 = 0xFFFFFFFFu, k3 = 0xFFFFFFFFu;
#pragma unroll 8
    for (int i = 0; i < 512; ++i) {
        const f32x4 qv = sp[4 * i + c];
        const float e = fmaxf(fmaf(ax, qv[0], fmaf(ay, qv[1], fmaf(az, qv[2], qv[3] + pp))), 0.f);
        const unsigned x = (__float_as_uint(e) & 0xFFFFF800u) | (unsigned)(4 * i + c);
        INS4(k0, k1, k2, k3, x);
    }
#pragma unroll
    for (int off = 1; off <= 2; off <<= 1) {
        const unsigned m0 = __shfl_xor(k0, off), m1 = __shfl_xor(k1, off);
        const unsigned m2 = __shfl_xor(k2, off), m3 = __shfl_xor(k3, off);
        INS4(k0, k1, k2, k3, m0); INS4(k0, k1, k2, k3, m1);
        INS4(k0, k1, k2, k3, m2); INS4(k0, k1, k2, k3, m3);
    }

    bool flag = false;
    float w0f = 0.f, w1f = 0.f, w2f = 0.f;
    int i0 = (int)(k0 & 2047u), i1 = (int)(k1 & 2047u), i2 = (int)(k2 & 2047u);
    if (c == 0) {
        const float v2t = __uint_as_float(k2 & 0xFFFFF800u);
        const float v3t = __uint_as_float(k3 & 0xFFFFF800u);
        flag = (v3t - v2t) <= fmaf(v3t, 1e-3f, 2.5e-4f);
        const double dpx = (double)px, dpy = (double)py, dpz = (double)pz;
        const f32x4 s0 = sp[i0], s1 = sp[i1], s2 = sp[i2];
        double d0 = (dpx - s0[0]) * (dpx - s0[0]) + (dpy - s0[1]) * (dpy - s0[1]) + (dpz - s0[2]) * (dpz - s0[2]);
        double d1 = (dpx - s1[0]) * (dpx - s1[0]) + (dpy - s1[1]) * (dpy - s1[1]) + (dpz - s1[2]) * (dpz - s1[2]);
        double d2 = (dpx - s2[0]) * (dpx - s2[0]) + (dpy - s2[1]) * (dpy - s2[1]) + (dpz - s2[2]) * (dpz - s2[2]);
        if (d1 < d0 || (d1 == d0 && i1 < i0)) { double td = d0; d0 = d1; d1 = td; int ti = i0; i0 = i1; i1 = ti; }
        if (d2 < d1 || (d2 == d1 && i2 < i1)) { double td = d1; d1 = d2; d2 = td; int ti = i1; i1 = i2; i2 = ti; }
        if (d1 < d0 || (d1 == d0 && i1 < i0)) { double td = d0; d0 = d1; d1 = td; int ti = i0; i0 = i1; i1 = ti; }
        const double r0 = 1.0 / (d0 + 1e-8), r1 = 1.0 / (d1 + 1e-8), r2 = 1.0 / (d2 + 1e-8);
        const double rs = 1.0 / (r0 + r1 + r2);
        w0f = (float)(r0 * rs); w1f = (float)(r1 * rs); w2f = (float)(r2 * rs);
    }
    const int src = (t & 63) & ~3;
    w0f = __shfl(w0f, src); w1f = __shfl(w1f, src); w2f = __shfl(w2f, src);
    i0 = __shfl(i0, src); i1 = __shfl(i1, src); i2 = __shfl(i2, src);

    {
        const unsigned long long bal = __ballot(flag);
        if (bal) {
            const int l = t & 63;
            int base = 0;
            if (l == 0) base = atomicAdd(flagcount, __popcll(bal));
            base = __shfl(base, 0);
            if (flag) {
                const int pre = __popcll(bal & ((1ull << l) - 1ull));
                flaglist[base + pre] = (bb << 13) | nq;
            }
        }
    }

    const f32x4* row0 = (const f32x4*)(p2t + ((size_t)(bb * kS) + i0) * kD2);
    const f32x4* row1 = (const f32x4*)(p2t + ((size_t)(bb * kS) + i1) * kD2);
    const f32x4* row2 = (const f32x4*)(p2t + ((size_t)(bb * kS) + i2) * kD2);
    unsigned short* dst = xt + ((size_t)(bb * kN) + nq) * kCin;
#pragma unroll 4
    for (int j = 0; j < 16; ++j) {
        const int ch = c + 4 * j;
        f32x4 v = w0f * row0[ch] + w1f * row1[ch] + w2f * row2[ch];
        u16x4 u = {f2bf(v[0]), f2bf(v[1]), f2bf(v[2]), f2bf(v[3])};
        *(u16x4*)(dst + ch * 4) = u;
    }
}
#undef INS4

// ---- Exact fp64 redo for uncertified queries (one wave per query) ---------
__global__ __launch_bounds__(256) void knn_fallback_kernel(
    const float* __restrict__ xyz1, const f32x4* __restrict__ spk,
    const float* __restrict__ p2t, unsigned short* __restrict__ xt,
    const int* __restrict__ flaglist, const int* __restrict__ flagcount)
{
    const int cnt = *flagcount;
    const int t = threadIdx.x;
    const int w = t >> 6, l = t & 63;
    for (int idx = blockIdx.x * 4 + w; idx < cnt; idx += gridDim.x * 4) {
        const int code = flaglist[idx];
        const int b = code >> 13, n = code & 8191;
        const float* x1 = xyz1 + b * 3 * kN;
        const double px = (double)x1[n], py = (double)x1[kN + n], pz = (double)x1[2 * kN + n];
        double d0 = 1e300, d1 = 1e300, d2 = 1e300;
        int i0 = 0, i1 = 0, i2 = 0;
        for (int s = l; s < kS; s += 64) {
            const f32x4 q = spk[b * kS + s];
            const double ex = px - (double)q[0], ey = py - (double)q[1], ez = pz - (double)q[2];
            const double d = ex * ex + ey * ey + ez * ez;
            if (d < d2) {
                if (d < d1) {
                    if (d < d0) { d2 = d1; i2 = i1; d1 = d0; i1 = i0; d0 = d; i0 = s; }
                    else        { d2 = d1; i2 = i1; d1 = d;  i1 = s; }
                } else          { d2 = d;  i2 = s; }
            }
        }
#pragma unroll
        for (int off = 1; off < 64; off <<= 1) {
            double pd0 = __shfl_xor(d0, off), pd1 = __shfl_xor(d1, off), pd2 = __shfl_xor(d2, off);
            int pi0 = __shfl_xor(i0, off), pi1 = __shfl_xor(i1, off), pi2 = __shfl_xor(i2, off);
#pragma unroll
            for (int m = 0; m < 3; ++m) {
                const double pd = (m == 0) ? pd0 : (m == 1) ? pd1 : pd2;
                const int pi = (m == 0) ? pi0 : (m == 1) ? pi1 : pi2;
                if (pd < d2 || (pd == d2 && pi < i2)) {
                    if (pd < d1 || (pd == d1 && pi < i1)) {
                        if (pd < d0 || (pd == d0 && pi < i0)) {
                            d2 = d1; i2 = i1; d1 = d0; i1 = i0; d0 = pd; i0 = pi;
                        } else { d2 = d1; i2 = i1; d1 = pd; i1 = pi; }
                    } else { d2 = pd; i2 = pi; }
                }
            }
        }
        const double r0 = 1.0 / (d0 + 1e-8), r1 = 1.0 / (d1 + 1e-8), r2 = 1.0 / (d2 + 1e-8);
        const double rs = 1.0 / (r0 + r1 + r2);
        const float w0f = (float)(r0 * rs), w1f = (float)(r1 * rs), w2f = (float)(r2 * rs);
        const f32x4* row0 = (const f32x4*)(p2t + ((size_t)(b * kS) + i0) * kD2);
        const f32x4* row1 = (const f32x4*)(p2t + ((size_t)(b * kS) + i1) * kD2);
        const f32x4* row2 = (const f32x4*)(p2t + ((size_t)(b * kS) + i2) * kD2);
        const f32x4 v = w0f * row0[l] + w1f * row1[l] + w2f * row2[l];
        u16x4 u = {f2bf(v[0]), f2bf(v[1]), f2bf(v[2]), f2bf(v[3])};
        *(u16x4*)(xt + ((size_t)(b * kN) + n) * kCin + l * 4) = u;
    }
}

// ---------------- bf16 MFMA GEMM + BN-stats, double-buffered ---------------
// Stats to 64 replicated accumulators (r13 atomic decontention, validated).
// BNRELU: scale/shift computed IN-KERNEL from the 64 replicas + g/be
// (folds the bn_finalize dispatch; r11-validated pattern).
__device__ inline int swz(int row, int ks) {   // ushort index of a 16B slot
    return row * 32 + ((ks ^ ((row >> 1) & 3)) << 3);
}

template <int K, int MTOT, bool BNRELU, int OUTMODE, bool STATS>
__global__ __launch_bounds__(256) void gemm_bn_kernel(
    const unsigned short* __restrict__ Wbf, const unsigned short* __restrict__ X,
    const float* __restrict__ bn_repl, const float* __restrict__ bn_g,
    const float* __restrict__ bn_be,
    unsigned short* __restrict__ Yb, float* __restrict__ Yf,
    float* __restrict__ repl)
{
    constexpr int BM = 128, BN = 64;
    __shared__ unsigned short Al[2][BM * 32], Bl[2][BN * 32];   // 16+8 KB
    __shared__ float ssum[BM], ssq[BM];
    __shared__ float s_sc[K], s_sh[K];
    const int t = threadIdx.x;
    const int bn = blockIdx.x * BN, bo = blockIdx.y * BM, b = blockIdx.z;
    const int l = t & 63, w = t >> 6;
    const int wm = (w >> 1) * 64, wn = (w & 1) * 32;
    const int lrow = l & 15, lks = l >> 4;

    if constexpr (BNRELU) {
        if (t < K) {   // folded bn_finalize: sum 64 replicas -> scale/shift
            float s = 0.f, q = 0.f;
#pragma unroll 8
            for (int r = 0; r < kReps; ++r) {
                s += bn_repl[(size_t)r * 2 * K + t];
                q += bn_repl[(size_t)r * 2 * K + K + t];
            }
            const float invn = 1.0f / 65536.0f;
            const float mean = s * invn;
            const float var = q * invn - mean * mean;   // biased var
            const float sc = bn_g[t] * rsqrtf(var + kEps);
            s_sc[t] = sc;
            s_sh[t] = fmaf(-mean, sc, bn_be[t]);
        }
    }
    if constexpr (STATS) {
        if (t < BM) { ssum[t] = 0.f; ssq[t] = 0.f; }
    }
    __syncthreads();

    const int mA0 = t >> 2, ksA = t & 3;
    const int mA1 = mA0 + 64;
    const int nB = t >> 2, ksB = t & 3;
    bf16x8 rA0, rA1, rB;

    auto load_tile = [&](int k0) {
        rA0 = *(const bf16x8*)(Wbf + (size_t)(bo + mA0) * K + k0 + ksA * 8);
        rA1 = *(const bf16x8*)(Wbf + (size_t)(bo + mA1) * K + k0 + ksA * 8);
        rB  = *(const bf16x8*)(X + ((size_t)(b * kN) + bn + nB) * K + k0 + ksB * 8);
    };
    auto write_tile = [&](int buf, int k0) {
        *(bf16x8*)(&Al[buf][0] + swz(mA0, ksA)) = rA0;
        *(bf16x8*)(&Al[buf][0] + swz(mA1, ksA)) = rA1;
        bf16x8 v = rB;
        if constexpr (BNRELU) {
#pragma unroll
            for (int j = 0; j < 8; ++j) {
                const int ch = k0 + ksB * 8 + j;
                float f = fmaxf(fmaf(bf2f((unsigned short)v[j]), s_sc[ch], s_sh[ch]), 0.f);
                v[j] = (short)f2bf(f);
            }
        }
        *(bf16x8*)(&Bl[buf][0] + swz(nB, ksB)) = v;
    };

    f32x4 acc[4][2] = {};
    load_tile(0);
    write_tile(0, 0);
    __syncthreads();
    int cur = 0;
    for (int k0 = 32; k0 <= K; k0 += 32) {
        if (k0 < K) load_tile(k0);             // prefetch next tile to regs
        bf16x8 af[4], bfr[2];
#pragma unroll
        for (int f = 0; f < 4; ++f) af[f]  = *(const bf16x8*)(&Al[cur][0] + swz(wm + f * 16 + lrow, lks));
#pragma unroll
        for (int f = 0; f < 2; ++f) bfr[f] = *(const bf16x8*)(&Bl[cur][0] + swz(wn + f * 16 + lrow, lks));
#pragma unroll
        for (int mi = 0; mi < 4; ++mi)
#pragma unroll
            for (int ni = 0; ni < 2; ++ni)
                acc[mi][ni] = __builtin_amdgcn_mfma_f32_16x16x32_bf16(af[mi], bfr[ni], acc[mi][ni], 0, 0, 0);
        if (k0 < K) { write_tile(cur ^ 1, k0); cur ^= 1; }
        __syncthreads();
    }

    if constexpr (STATS) {
#pragma unroll
        for (int mi = 0; mi < 4; ++mi) {
#pragma unroll
            for (int r = 0; r < 4; ++r) {
                float ps = 0.f, pq = 0.f;
#pragma unroll
                for (int ni = 0; ni < 2; ++ni) { float v = acc[mi][ni][r]; ps += v; pq += v * v; }
#pragma unroll
                for (int off = 1; off < 16; off <<= 1) { ps += __shfl_xor(ps, off); pq += __shfl_xor(pq, off); }
                if (lrow == 0) {
                    const int m = wm + mi * 16 + lks * 4 + r;
                    atomicAdd(&ssum[m], ps); atomicAdd(&ssq[m], pq);
                }
            }
        }
    }

    if constexpr (OUTMODE == 0) {
#pragma unroll
        for (int mi = 0; mi < 4; ++mi)
#pragma unroll
            for (int ni = 0; ni < 2; ++ni) {
                const int m = bo + wm + mi * 16 + lks * 4;
                const int n = bn + wn + ni * 16 + lrow;
                u16x4 u = {f2bf(acc[mi][ni][0]), f2bf(acc[mi][ni][1]),
                           f2bf(acc[mi][ni][2]), f2bf(acc[mi][ni][3])};
                *(u16x4*)(Yb + ((size_t)(b * kN) + n) * MTOT + m) = u;
            }
    } else {
#pragma unroll
        for (int mi = 0; mi < 4; ++mi)
#pragma unroll
            for (int ni = 0; ni < 2; ++ni) {
                const int n = bn + wn + ni * 16 + lrow;
#pragma unroll
                for (int r = 0; r < 4; ++r) {
                    const int m = bo + wm + mi * 16 + lks * 4 + r;
                    Yf[((size_t)(b * MTOT) + m) * kN + n] = acc[mi][ni][r];
                }
            }
    }
    if constexpr (STATS) {
        __syncthreads();
        if (t < BM) {
            const int rep = (blockIdx.x + blockIdx.z * 8) & (kReps - 1);
            float* rp = repl + (size_t)rep * (2 * MTOT);
            atomicAdd(&rp[bo + t], ssum[t]);
            atomicAdd(&rp[MTOT + bo + t], ssq[t]);
        }
    }
}

// -------- Final in-place BN+ReLU on d_out (folds bn_finalize) --------------
__global__ __launch_bounds__(256) void bn_relu_out_kernel(
    float* __restrict__ out, const float* __restrict__ bn_repl,
    const float* __restrict__ bn_g, const float* __restrict__ bn_be)
{
    __shared__ float ssc[kM1], ssh[kM1];
    const int t = threadIdx.x;
    if (t < kM1) {
        float s = 0.f, q = 0.f;
#pragma unroll 8
        for (int r = 0; r < kReps; ++r) {
            s += bn_repl[(size_t)r * 2 * kM1 + t];
            q += bn_repl[(size_t)r * 2 * kM1 + kM1 + t];
        }
        const float invn = 1.0f / 65536.0f;
        const float mean = s * invn;
        const float var = q * invn - mean * mean;   // biased var
        const float sc = bn_g[t] * rsqrtf(var + kEps);
        ssc[t] = sc;
        ssh[t] = fmaf(-mean, sc, bn_be[t]);
    }
    __syncthreads();
    const int total = kB * kM1 * kN / 4;
    for (int idx = blockIdx.x * blockDim.x + t; idx < total; idx += gridDim.x * blockDim.x) {
        const int p = (idx >> 11) & 127;
        const float sc = ssc[p], sh = ssh[p];
        f32x4 v = ((f32x4*)out)[idx];
#pragma unroll
        for (int j = 0; j < 4; ++j) v[j] = fmaxf(fmaf(v[j], sc, sh), 0.f);
        ((f32x4*)out)[idx] = v;
    }
}

extern "C" void kernel_launch(void* const* d_in, const int* in_sizes, int n_in,
                              void* d_out, int out_size, void* d_ws, size_t ws_size,
                              hipStream_t stream)
{
    const float* xyz1    = (const float*)d_in[0];
    const float* xyz2    = (const float*)d_in[1];
    const float* points1 = (const float*)d_in[2];
    const float* points2 = (const float*)d_in[3];
    const float* w0      = (const float*)d_in[4];
    // d_in[5] = b0, d_in[9] = b1: conv biases cancel in BatchNorm -> unused
    const float* g0      = (const float*)d_in[6];
    const float* be0     = (const float*)d_in[7];
    const float* w1      = (const float*)d_in[8];
    const float* g1      = (const float*)d_in[10];
    const float* be1     = (const float*)d_in[11];
    float* out = (float*)d_out;

    char* ws = (char*)d_ws;
    unsigned short* xt  = (unsigned short*)ws;                           // 48 MiB  [B][N][384] bf16
    float* p2t          = (float*)(ws + (size_t)50331648);               // 16 MiB  [B][S][256] f32
    unsigned short* y0t = (unsigned short*)(ws + (size_t)67108864);      // 32 MiB  [B][N][256] bf16
    float* repl0        = (float*)(ws + (size_t)100663296);              // 128 KiB [64][512]
    float* repl1        = (float*)(ws + (size_t)100794368);              // 64 KiB  [64][256]
    float* smallstats   = (float*)(ws + (size_t)100859904);              // 772 floats
    f32x4* spk          = (f32x4*)(ws + (size_t)104857600);              // 256 KiB [B][S] packed
    int*  flaglist      = (int*)(ws + (size_t)105906176);                // 256 KiB worst-case
    unsigned short* w0bf = (unsigned short*)(ws + (size_t)106954752);    // 192 KiB [256][384] bf16
    unsigned short* w1bf = (unsigned short*)(ws + (size_t)107151360);    // 64 KiB  [128][256] bf16
    int*  flagcount = (int*)(smallstats + 768);

    prep_kernel<<<3104, 256, 0, stream>>>(points2, p2t, points1, xt, xyz2, spk,
                                          repl0, smallstats, w0, w0bf, w1, w1bf);
    knn_interp_kernel<<<1024, 256, 0, stream>>>(xyz1, spk, p2t, xt, flaglist, flagcount);
    knn_fallback_kernel<<<1024, 256, 0, stream>>>(xyz1, spk, p2t, xt, flaglist, flagcount);
    gemm_bn_kernel<kCin, kM0, false, 0, true><<<dim3(128, 2, 8), 256, 0, stream>>>(
        w0bf, xt, nullptr, nullptr, nullptr, y0t, nullptr, repl0);
    gemm_bn_kernel<kM0, kM1, true, 1, true><<<dim3(128, 1, 8), 256, 0, stream>>>(
        w1bf, y0t, repl0, g0, be0, nullptr, out, repl1);
    bn_relu_out_kernel<<<2048, 256, 0, stream>>>(out, repl1, g1, be1);
}